// Round 1
// baseline (9004.957 us; speedup 1.0000x reference)
//
#include <hip/hip_runtime.h>

#define SC 20
#define EDIM 16
#define HDIM 10
#define CO 12
#define NG 40          // 4*H
#define VROWS 256
#define RSTRIDE 20     // padded LDS row stride (floats), keeps 16B alignment

#if __has_builtin(__builtin_amdgcn_exp2f)
#define EXP2F(x) __builtin_amdgcn_exp2f(x)
#else
#define EXP2F(x) exp2f(x)
#endif
#if __has_builtin(__builtin_amdgcn_rcpf)
#define RCPF(x) __builtin_amdgcn_rcpf(x)
#else
#define RCPF(x) (1.0f / (x))
#endif

#define L2E 1.44269504088896340736f

__device__ __forceinline__ float fast_sig(float x) {
    return RCPF(1.0f + EXP2F(-x * L2E));
}
__device__ __forceinline__ float fast_tanh(float x) {
    float e = EXP2F(x * (2.0f * L2E));
    return 1.0f - 2.0f * RCPF(1.0f + e);
}

__device__ __forceinline__ void load_row_lds(const float* emb_s, int idx, float* dst) {
    const float4* p = (const float4*)(emb_s + idx * RSTRIDE);
    float4 a = p[0], b = p[1], c = p[2], d = p[3];
    dst[0] = a.x; dst[1] = a.y; dst[2] = a.z; dst[3] = a.w;
    dst[4] = b.x; dst[5] = b.y; dst[6] = b.z; dst[7] = b.w;
    dst[8] = c.x; dst[9] = c.y; dst[10] = c.z; dst[11] = c.w;
    dst[12] = d.x; dst[13] = d.y; dst[14] = d.z; dst[15] = d.w;
}

__global__ __launch_bounds__(256, 2) void cnn_lstm_kernel(
    const int* __restrict__ inp, const float* __restrict__ emb,
    const float* __restrict__ k2, const float* __restrict__ k3,
    const float* __restrict__ k4,
    const float* __restrict__ wfw, const float* __restrict__ bfw,
    const float* __restrict__ wbw, const float* __restrict__ bbw,
    float* __restrict__ out)
{
    __shared__ float emb_s[(VROWS + 1) * RSTRIDE];
    const int tid = threadIdx.x;

    // stage embeddings into LDS (padded rows), plus a zero row at idx==VROWS
    {
        const float4* ep = (const float4*)(emb + tid * EDIM);
        float4 v0 = ep[0], v1 = ep[1], v2 = ep[2], v3 = ep[3];
        float4* dp = (float4*)(emb_s + tid * RSTRIDE);
        dp[0] = v0; dp[1] = v1; dp[2] = v2; dp[3] = v3;
        if (tid < EDIM) emb_s[VROWS * RSTRIDE + tid] = 0.0f;
    }
    __syncthreads();

    const int dir = blockIdx.x >> 8;          // 0 = forward, 1 = backward (block-uniform)
    const bool fw = (dir == 0);
    const int n = (blockIdx.x & 255) * 256 + tid;
    const int* inp_n = inp + n * SC;
    const float* wsel = fw ? wfw : wbw;
    const float* bsel = fw ? bfw : bbw;

    float win[4][EDIM];   // sliding enc window: win[3] = newest (highest char row)
    float h[HDIM], cs[HDIM];
    #pragma unroll
    for (int q = 0; q < HDIM; ++q) { h[q] = 0.0f; cs[q] = 0.0f; }

    // initial window = rows ct-3..ct for the first processed char position
    if (fw) {
        #pragma unroll
        for (int i = 0; i < 3; ++i)
            #pragma unroll
            for (int e = 0; e < EDIM; ++e) win[i][e] = 0.0f;
        load_row_lds(emb_s, inp_n[0], win[3]);
    } else {
        #pragma unroll
        for (int i = 0; i < 4; ++i)
            load_row_lds(emb_s, inp_n[SC - 4 + i], win[i]);
    }

    for (int t = 0; t < SC; ++t) {
        const int ct = fw ? t : (SC - 1 - t);   // char position processed this step

        // opaque copies: keep weight loads uniform (SGPR/s_load) but stop LICM
        // from hoisting ~900 scalar loads out of the loop (SGPR spill bomb)
        const float* wp = wsel;  asm volatile("" : "+s"(wp));
        const float* bp = bsel;  asm volatile("" : "+s"(bp));
        const float* k2p = k2;   asm volatile("" : "+s"(k2p));
        const float* k3p = k3;   asm volatile("" : "+s"(k3p));
        const float* k4p = k4;   asm volatile("" : "+s"(k4p));

        // ---- causal conv at char ct: out[f] = sum_tap sum_e enc[ct-k+1+tap][e]*ker[tap][e][f]
        float cc[CO];
        #pragma unroll
        for (int f = 0; f < CO; ++f) cc[f] = 0.0f;
        #pragma unroll
        for (int tap = 0; tap < 2; ++tap)
            #pragma unroll
            for (int e = 0; e < EDIM; ++e) {
                const float x = win[2 + tap][e];
                #pragma unroll
                for (int f = 0; f < 3; ++f) cc[f] += x * k2p[(tap * EDIM + e) * 3 + f];
            }
        #pragma unroll
        for (int tap = 0; tap < 3; ++tap)
            #pragma unroll
            for (int e = 0; e < EDIM; ++e) {
                const float x = win[1 + tap][e];
                #pragma unroll
                for (int f = 0; f < 4; ++f) cc[3 + f] += x * k3p[(tap * EDIM + e) * 4 + f];
            }
        #pragma unroll
        for (int tap = 0; tap < 4; ++tap)
            #pragma unroll
            for (int e = 0; e < EDIM; ++e) {
                const float x = win[tap][e];
                #pragma unroll
                for (int f = 0; f < 5; ++f) cc[7 + f] += x * k4p[(tap * EDIM + e) * 5 + f];
            }

        // ---- LSTM step: z = [cc, h] @ W + b ; gates i,j,f,o ; forget_bias=1
        float z[NG];
        #pragma unroll
        for (int g = 0; g < NG; ++g) z[g] = bp[g];
        #pragma unroll
        for (int d = 0; d < CO; ++d) {
            const float x = cc[d];
            #pragma unroll
            for (int g = 0; g < NG; ++g) z[g] += x * wp[d * NG + g];
        }
        #pragma unroll
        for (int d = 0; d < HDIM; ++d) {
            const float x = h[d];
            #pragma unroll
            for (int g = 0; g < NG; ++g) z[g] += x * wp[(CO + d) * NG + g];
        }
        #pragma unroll
        for (int q = 0; q < HDIM; ++q) {
            const float ig = fast_sig(z[q]);
            const float jg = fast_tanh(z[HDIM + q]);
            const float fg = fast_sig(z[2 * HDIM + q] + 1.0f);
            const float og = fast_sig(z[3 * HDIM + q]);
            cs[q] = fg * cs[q] + ig * jg;
            h[q]  = og * fast_tanh(cs[q]);
        }

        // ---- advance the window for the next step
        if (t < SC - 1) {
            if (fw) {
                #pragma unroll
                for (int i = 0; i < 3; ++i)
                    #pragma unroll
                    for (int e = 0; e < EDIM; ++e) win[i][e] = win[i + 1][e];
                load_row_lds(emb_s, inp_n[ct + 1], win[3]);
            } else {
                #pragma unroll
                for (int i = 3; i > 0; --i)
                    #pragma unroll
                    for (int e = 0; e < EDIM; ++e) win[i][e] = win[i - 1][e];
                const int r = ct - 4;
                const int idx = (r >= 0) ? inp_n[r] : VROWS;  // zero row when out of range
                load_row_lds(emb_s, idx, win[0]);
            }
        }
    }

    // out[n, dir*H + q]
    #pragma unroll
    for (int q = 0; q < HDIM; ++q)
        out[n * (2 * HDIM) + dir * HDIM + q] = h[q];
}

extern "C" void kernel_launch(void* const* d_in, const int* in_sizes, int n_in,
                              void* d_out, int out_size, void* d_ws, size_t ws_size,
                              hipStream_t stream) {
    const int*   inp = (const int*)d_in[0];
    const float* emb = (const float*)d_in[1];
    const float* k2  = (const float*)d_in[2];
    const float* k3  = (const float*)d_in[3];
    const float* k4  = (const float*)d_in[4];
    const float* wfw = (const float*)d_in[5];
    const float* bfw = (const float*)d_in[6];
    const float* wbw = (const float*)d_in[7];
    const float* bbw = (const float*)d_in[8];
    float* out = (float*)d_out;

    // 131072 threads: one per (sequence, direction). dir = blockIdx>>8 (block-uniform).
    cnn_lstm_kernel<<<dim3(512), dim3(256), 0, stream>>>(
        inp, emb, k2, k3, k4, wfw, bfw, wbw, bbw, out);
}

// Round 2
// 4184.496 us; speedup vs baseline: 2.1520x; 2.1520x over previous
//
#include <hip/hip_runtime.h>

#define SC 20
#define EDIM 16
#define HDIM 10
#define CO 12
#define NG 40          // 4*H
#define VOCAB 256
#define TROW 48        // floats per vocab row of ctab: 4 ages x 12 feats
#define SENT VOCAB     // sentinel zero row index

#if __has_builtin(__builtin_amdgcn_exp2f)
#define EXP2F(x) __builtin_amdgcn_exp2f(x)
#else
#define EXP2F(x) exp2f(x)
#endif
#if __has_builtin(__builtin_amdgcn_rcpf)
#define RCPF(x) __builtin_amdgcn_rcpf(x)
#else
#define RCPF(x) (1.0f / (x))
#endif

#define L2E 1.44269504088896340736f

__device__ __forceinline__ float fast_sig(float x) {
    return RCPF(1.0f + EXP2F(-x * L2E));
}
__device__ __forceinline__ float fast_tanh(float x) {
    float e = EXP2F(x * (2.0f * L2E));
    return 1.0f - 2.0f * RCPF(1.0f + e);
}
__device__ __forceinline__ void add4(float4& a, const float4 b) {
    a.x += b.x; a.y += b.y; a.z += b.z; a.w += b.w;
}
// zz[4j..4j+3] += x * wrow[4j..4j+3], j=0..9  (wrow uniform -> s_load_dwordx4)
__device__ __forceinline__ void gemv_row(float* zz, float x, const float* wrow) {
    const float4* wv = (const float4*)wrow;
    #pragma unroll
    for (int j = 0; j < 10; ++j) {
        float4 w = wv[j];
        zz[4 * j + 0] += x * w.x;
        zz[4 * j + 1] += x * w.y;
        zz[4 * j + 2] += x * w.z;
        zz[4 * j + 3] += x * w.w;
    }
}

__global__ __launch_bounds__(256, 2) void cnn_lstm_kernel(
    const int* __restrict__ inp, const float* __restrict__ emb,
    const float* __restrict__ k2, const float* __restrict__ k3,
    const float* __restrict__ k4,
    const float* __restrict__ wfw, const float* __restrict__ bfw,
    const float* __restrict__ wbw, const float* __restrict__ bbw,
    float* __restrict__ out)
{
    // ctab[v][age][f]: contribution of a char v seen `age` steps ago to the
    // 12 conv outputs at the current position. age=2 has f0..2 == 0,
    // age=3 has f0..6 == 0. Row SENT is all zeros (left padding).
    __shared__ float ctab[(VOCAB + 1) * TROW];

    const int tid = threadIdx.x;

    // ---- build table: thread v = tid handles one vocab row -----------------
    {
        float er[EDIM];
        const float4* ep = (const float4*)(emb + tid * EDIM);
        float4 e0 = ep[0], e1 = ep[1], e2 = ep[2], e3 = ep[3];
        er[0] = e0.x; er[1] = e0.y; er[2] = e0.z; er[3] = e0.w;
        er[4] = e1.x; er[5] = e1.y; er[6] = e1.z; er[7] = e1.w;
        er[8] = e2.x; er[9] = e2.y; er[10] = e2.z; er[11] = e2.w;
        er[12] = e3.x; er[13] = e3.y; er[14] = e3.z; er[15] = e3.w;

        float* dst = ctab + tid * TROW;
        #pragma unroll
        for (int dlt = 0; dlt < 4; ++dlt) {
            float o[12];
            #pragma unroll
            for (int f = 0; f < 12; ++f) o[f] = 0.0f;
            const int tap2 = 1 - dlt, tap3 = 2 - dlt, tap4 = 3 - dlt;
            if (tap2 >= 0) {
                #pragma unroll
                for (int e = 0; e < EDIM; ++e) {
                    const float x = er[e];
                    #pragma unroll
                    for (int f = 0; f < 3; ++f) o[f] += x * k2[(tap2 * EDIM + e) * 3 + f];
                }
            }
            if (tap3 >= 0) {
                #pragma unroll
                for (int e = 0; e < EDIM; ++e) {
                    const float x = er[e];
                    #pragma unroll
                    for (int f = 0; f < 4; ++f) o[3 + f] += x * k3[(tap3 * EDIM + e) * 4 + f];
                }
            }
            {
                #pragma unroll
                for (int e = 0; e < EDIM; ++e) {
                    const float x = er[e];
                    #pragma unroll
                    for (int f = 0; f < 5; ++f) o[7 + f] += x * k4[(tap4 * EDIM + e) * 5 + f];
                }
            }
            #pragma unroll
            for (int f = 0; f < 12; ++f) dst[dlt * 12 + f] = o[f];
        }
    }
    if (tid < TROW) ctab[VOCAB * TROW + tid] = 0.0f;  // sentinel zero row
    __syncthreads();

    // ---- per-(sequence, direction) LSTM ------------------------------------
    const int dir = blockIdx.x >> 8;              // block-uniform
    const bool fw = (dir == 0);
    const int n = (blockIdx.x & 255) * 256 + tid;
    const int* inp_n = inp + n * SC;
    const float* wsel = fw ? wfw : wbw;
    const float* bsel = fw ? bfw : bbw;

    float h[HDIM], cs[HDIM];
    #pragma unroll
    for (int q = 0; q < HDIM; ++q) { h[q] = 0.0f; cs[q] = 0.0f; }

    // rolling chars at age 0..3 (a0 = current position's char)
    int a0, a1, a2, a3;
    if (fw) {
        a0 = inp_n[0]; a1 = SENT; a2 = SENT; a3 = SENT;
    } else {
        a0 = inp_n[SC - 1]; a1 = inp_n[SC - 2]; a2 = inp_n[SC - 3]; a3 = inp_n[SC - 4];
    }

    for (int t = 0; t < SC; ++t) {
        // opaque copies: weights stay uniform (s_load) but LICM can't hoist
        // all ~900 scalar loads out of the loop (SGPR spill bomb)
        const float* wp = wsel; asm volatile("" : "+s"(wp));
        const float* bp = bsel; asm volatile("" : "+s"(bp));

        // ---- conv outputs at this position: sum of 4 age-contributions ----
        const float4* r0 = (const float4*)(ctab + a0 * TROW);
        const float4* r1 = (const float4*)(ctab + a1 * TROW + 12);
        const float4* r2 = (const float4*)(ctab + a2 * TROW + 24);
        const float4* r3 = (const float4*)(ctab + a3 * TROW + 36);
        float4 C0 = r0[0], C1 = r0[1], C2 = r0[2];
        add4(C0, r1[0]); add4(C1, r1[1]); add4(C2, r1[2]);
        add4(C0, r2[0]); add4(C1, r2[1]); add4(C2, r2[2]);
        /* age-3 f0..3 block is all zeros -> skip */
        add4(C1, r3[1]); add4(C2, r3[2]);

        // ---- z = [cc, h] @ W + b ------------------------------------------
        float zz[NG];
        {
            const float4* bv = (const float4*)bp;
            #pragma unroll
            for (int j = 0; j < 10; ++j) {
                float4 b = bv[j];
                zz[4 * j + 0] = b.x; zz[4 * j + 1] = b.y;
                zz[4 * j + 2] = b.z; zz[4 * j + 3] = b.w;
            }
        }
        gemv_row(zz, C0.x, wp + 0 * NG);
        gemv_row(zz, C0.y, wp + 1 * NG);
        gemv_row(zz, C0.z, wp + 2 * NG);
        gemv_row(zz, C0.w, wp + 3 * NG);
        gemv_row(zz, C1.x, wp + 4 * NG);
        gemv_row(zz, C1.y, wp + 5 * NG);
        gemv_row(zz, C1.z, wp + 6 * NG);
        gemv_row(zz, C1.w, wp + 7 * NG);
        gemv_row(zz, C2.x, wp + 8 * NG);
        gemv_row(zz, C2.y, wp + 9 * NG);
        gemv_row(zz, C2.z, wp + 10 * NG);
        gemv_row(zz, C2.w, wp + 11 * NG);
        #pragma unroll
        for (int d = 0; d < HDIM; ++d)
            gemv_row(zz, h[d], wp + (CO + d) * NG);

        // ---- gates (tf order i, j, f, o; forget_bias = 1) ------------------
        #pragma unroll
        for (int q = 0; q < HDIM; ++q) {
            const float ig = fast_sig(zz[q]);
            const float jg = fast_tanh(zz[HDIM + q]);
            const float fg = fast_sig(zz[2 * HDIM + q] + 1.0f);
            const float og = fast_sig(zz[3 * HDIM + q]);
            cs[q] = fg * cs[q] + ig * jg;
            h[q] = og * fast_tanh(cs[q]);
        }

        // ---- advance rolling char window -----------------------------------
        if (t < SC - 1) {
            if (fw) {
                a3 = a2; a2 = a1; a1 = a0;
                a0 = inp_n[t + 1];
            } else {
                a0 = a1; a1 = a2; a2 = a3;
                const int idx = SC - 5 - t;     // (SC-1-t) - 4
                a3 = (idx >= 0) ? inp_n[idx] : SENT;
            }
        }
    }

    #pragma unroll
    for (int q = 0; q < HDIM; ++q)
        out[n * (2 * HDIM) + dir * HDIM + q] = h[q];
}

extern "C" void kernel_launch(void* const* d_in, const int* in_sizes, int n_in,
                              void* d_out, int out_size, void* d_ws, size_t ws_size,
                              hipStream_t stream) {
    const int*   inp = (const int*)d_in[0];
    const float* emb = (const float*)d_in[1];
    const float* k2  = (const float*)d_in[2];
    const float* k3  = (const float*)d_in[3];
    const float* k4  = (const float*)d_in[4];
    const float* wfw = (const float*)d_in[5];
    const float* bfw = (const float*)d_in[6];
    const float* wbw = (const float*)d_in[7];
    const float* bbw = (const float*)d_in[8];
    float* out = (float*)d_out;

    cnn_lstm_kernel<<<dim3(512), dim3(256), 0, stream>>>(
        inp, emb, k2, k3, k4, wfw, bfw, wbw, bbw, out);
}

// Round 3
// 2316.414 us; speedup vs baseline: 3.8875x; 1.8065x over previous
//
#include <hip/hip_runtime.h>

#define SC 20
#define EDIM 16
#define HDIM 10
#define CO 12
#define NG 40          // 4*H
#define VOCAB 256
#define TROW 52        // padded row stride (floats): 48 used + 4 pad -> 8 bank classes
#define SENT VOCAB     // sentinel zero row index
#define WFLOATS 920    // 22*40 weights + 40 bias per direction

#if __has_builtin(__builtin_amdgcn_exp2f)
#define EXP2F(x) __builtin_amdgcn_exp2f(x)
#else
#define EXP2F(x) exp2f(x)
#endif
#if __has_builtin(__builtin_amdgcn_rcpf)
#define RCPF(x) __builtin_amdgcn_rcpf(x)
#else
#define RCPF(x) (1.0f / (x))
#endif

#define L2E 1.44269504088896340736f

__device__ __forceinline__ float fast_sig(float x) {
    return RCPF(1.0f + EXP2F(-x * L2E));
}
__device__ __forceinline__ float fast_tanh(float x) {
    float e = EXP2F(x * (2.0f * L2E));
    return 1.0f - 2.0f * RCPF(1.0f + e);
}
__device__ __forceinline__ void add4(float4& a, const float4 b) {
    a.x += b.x; a.y += b.y; a.z += b.z; a.w += b.w;
}
// zz[4j..4j+3] += x * wrow[4j..4j+3]; wrow in LDS, same addr on all lanes
// -> ds_read_b128 broadcast (bank-conflict-free)
__device__ __forceinline__ void gemv_row(float* zz, float x, const float* wrow) {
    const float4* wv = (const float4*)wrow;
    #pragma unroll
    for (int j = 0; j < 10; ++j) {
        float4 w = wv[j];
        zz[4 * j + 0] += x * w.x;
        zz[4 * j + 1] += x * w.y;
        zz[4 * j + 2] += x * w.z;
        zz[4 * j + 3] += x * w.w;
    }
}

__global__ __launch_bounds__(256, 2) void cnn_lstm_kernel(
    const int* __restrict__ inp, const float* __restrict__ emb,
    const float* __restrict__ k2, const float* __restrict__ k3,
    const float* __restrict__ k4,
    const float* __restrict__ wfw, const float* __restrict__ bfw,
    const float* __restrict__ wbw, const float* __restrict__ bbw,
    float* __restrict__ out)
{
    // ctab[v][age][f]: contribution of char v seen `age` steps ago to the 12
    // conv outputs at the current position. Row SENT is all zeros.
    __shared__ float ctab[(VOCAB + 1) * TROW];        // ~53.5 KB
    // wlds[dir]: rows 0..21 = W (22 x 40, row-major), floats 880..919 = bias
    __shared__ float wlds[2 * WFLOATS];               // 7.36 KB

    const int tid = threadIdx.x;

    // ---- stage weights into LDS --------------------------------------------
    for (int i = tid; i < WFLOATS; i += 256) {
        const float vf = (i < 880) ? wfw[i] : bfw[i - 880];
        const float vb = (i < 880) ? wbw[i] : bbw[i - 880];
        wlds[i] = vf;
        wlds[WFLOATS + i] = vb;
    }

    // ---- build ctab: thread v = tid handles one vocab row ------------------
    {
        float er[EDIM];
        const float4* ep = (const float4*)(emb + tid * EDIM);
        float4 e0 = ep[0], e1 = ep[1], e2 = ep[2], e3 = ep[3];
        er[0] = e0.x; er[1] = e0.y; er[2] = e0.z; er[3] = e0.w;
        er[4] = e1.x; er[5] = e1.y; er[6] = e1.z; er[7] = e1.w;
        er[8] = e2.x; er[9] = e2.y; er[10] = e2.z; er[11] = e2.w;
        er[12] = e3.x; er[13] = e3.y; er[14] = e3.z; er[15] = e3.w;

        float* dst = ctab + tid * TROW;
        #pragma unroll
        for (int dlt = 0; dlt < 4; ++dlt) {
            float o[12];
            #pragma unroll
            for (int f = 0; f < 12; ++f) o[f] = 0.0f;
            const int tap2 = 1 - dlt, tap3 = 2 - dlt, tap4 = 3 - dlt;
            if (tap2 >= 0) {
                #pragma unroll
                for (int e = 0; e < EDIM; ++e) {
                    const float x = er[e];
                    #pragma unroll
                    for (int f = 0; f < 3; ++f) o[f] += x * k2[(tap2 * EDIM + e) * 3 + f];
                }
            }
            if (tap3 >= 0) {
                #pragma unroll
                for (int e = 0; e < EDIM; ++e) {
                    const float x = er[e];
                    #pragma unroll
                    for (int f = 0; f < 4; ++f) o[3 + f] += x * k3[(tap3 * EDIM + e) * 4 + f];
                }
            }
            {
                #pragma unroll
                for (int e = 0; e < EDIM; ++e) {
                    const float x = er[e];
                    #pragma unroll
                    for (int f = 0; f < 5; ++f) o[7 + f] += x * k4[(tap4 * EDIM + e) * 5 + f];
                }
            }
            #pragma unroll
            for (int f = 0; f < 12; ++f) dst[dlt * 12 + f] = o[f];
        }
    }
    if (tid < TROW) ctab[VOCAB * TROW + tid] = 0.0f;  // sentinel zero row
    __syncthreads();

    // ---- per-(sequence, direction) LSTM ------------------------------------
    const int dir = blockIdx.x >> 8;              // block-uniform
    const bool fw = (dir == 0);
    const int n = (blockIdx.x & 255) * 256 + tid;
    const int* inp_n = inp + n * SC;
    const float* ws = wlds + dir * WFLOATS;       // W rows (LDS)
    const float* bs = ws + 880;                   // bias (LDS)

    float h[HDIM], cs[HDIM];
    #pragma unroll
    for (int q = 0; q < HDIM; ++q) { h[q] = 0.0f; cs[q] = 0.0f; }

    // rolling chars at age 0..3 (a0 = current position's char)
    int a0, a1, a2, a3;
    if (fw) {
        a0 = inp_n[0]; a1 = SENT; a2 = SENT; a3 = SENT;
    } else {
        a0 = inp_n[SC - 1]; a1 = inp_n[SC - 2]; a2 = inp_n[SC - 3]; a3 = inp_n[SC - 4];
    }

    for (int t = 0; t < SC; ++t) {
        // ---- conv outputs at this position: sum of 4 age-contributions ----
        const float4* r0 = (const float4*)(ctab + a0 * TROW);
        const float4* r1 = (const float4*)(ctab + a1 * TROW + 12);
        const float4* r2 = (const float4*)(ctab + a2 * TROW + 24);
        const float4* r3 = (const float4*)(ctab + a3 * TROW + 36);
        float4 C0 = r0[0], C1 = r0[1], C2 = r0[2];
        add4(C0, r1[0]); add4(C1, r1[1]); add4(C2, r1[2]);
        add4(C0, r2[0]); add4(C1, r2[1]); add4(C2, r2[2]);
        /* age-3 f0..3 block is all zeros -> skip */
        add4(C1, r3[1]); add4(C2, r3[2]);

        // ---- z = [cc, h] @ W + b (weights broadcast from LDS) --------------
        float zz[NG];
        {
            const float4* bv = (const float4*)bs;
            #pragma unroll
            for (int j = 0; j < 10; ++j) {
                float4 b = bv[j];
                zz[4 * j + 0] = b.x; zz[4 * j + 1] = b.y;
                zz[4 * j + 2] = b.z; zz[4 * j + 3] = b.w;
            }
        }
        gemv_row(zz, C0.x, ws + 0 * NG);
        gemv_row(zz, C0.y, ws + 1 * NG);
        gemv_row(zz, C0.z, ws + 2 * NG);
        gemv_row(zz, C0.w, ws + 3 * NG);
        gemv_row(zz, C1.x, ws + 4 * NG);
        gemv_row(zz, C1.y, ws + 5 * NG);
        gemv_row(zz, C1.z, ws + 6 * NG);
        gemv_row(zz, C1.w, ws + 7 * NG);
        gemv_row(zz, C2.x, ws + 8 * NG);
        gemv_row(zz, C2.y, ws + 9 * NG);
        gemv_row(zz, C2.z, ws + 10 * NG);
        gemv_row(zz, C2.w, ws + 11 * NG);
        #pragma unroll
        for (int d = 0; d < HDIM; ++d)
            gemv_row(zz, h[d], ws + (CO + d) * NG);

        // ---- gates (tf order i, j, f, o; forget_bias = 1) ------------------
        #pragma unroll
        for (int q = 0; q < HDIM; ++q) {
            const float ig = fast_sig(zz[q]);
            const float jg = fast_tanh(zz[HDIM + q]);
            const float fg = fast_sig(zz[2 * HDIM + q] + 1.0f);
            const float og = fast_sig(zz[3 * HDIM + q]);
            cs[q] = fg * cs[q] + ig * jg;
            h[q] = og * fast_tanh(cs[q]);
        }

        // ---- advance rolling char window -----------------------------------
        if (t < SC - 1) {
            if (fw) {
                a3 = a2; a2 = a1; a1 = a0;
                a0 = inp_n[t + 1];
            } else {
                a0 = a1; a1 = a2; a2 = a3;
                const int idx = SC - 5 - t;     // (SC-1-t) - 4
                a3 = (idx >= 0) ? inp_n[idx] : SENT;
            }
        }
    }

    #pragma unroll
    for (int q = 0; q < HDIM; ++q)
        out[n * (2 * HDIM) + dir * HDIM + q] = h[q];
}

extern "C" void kernel_launch(void* const* d_in, const int* in_sizes, int n_in,
                              void* d_out, int out_size, void* d_ws, size_t ws_size,
                              hipStream_t stream) {
    const int*   inp = (const int*)d_in[0];
    const float* emb = (const float*)d_in[1];
    const float* k2  = (const float*)d_in[2];
    const float* k3  = (const float*)d_in[3];
    const float* k4  = (const float*)d_in[4];
    const float* wfw = (const float*)d_in[5];
    const float* bfw = (const float*)d_in[6];
    const float* wbw = (const float*)d_in[7];
    const float* bbw = (const float*)d_in[8];
    float* out = (float*)d_out;

    cnn_lstm_kernel<<<dim3(512), dim3(256), 0, stream>>>(
        inp, emb, k2, k3, k4, wfw, bfw, wbw, bbw, out);
}

// Round 4
// 1652.412 us; speedup vs baseline: 5.4496x; 1.4018x over previous
//
#include <hip/hip_runtime.h>

#define SC 20
#define EDIM 16
#define HDIM 10
#define CO 12
#define NG 40          // 4*H
#define VOCAB 256
#define TROW 52        // padded ctab row stride (floats)
#define SENT VOCAB     // sentinel zero row index
#define WFLOATS 920    // 22*40 weights + 40 bias per direction

#if __has_builtin(__builtin_amdgcn_exp2f)
#define EXP2F(x) __builtin_amdgcn_exp2f(x)
#else
#define EXP2F(x) exp2f(x)
#endif
#if __has_builtin(__builtin_amdgcn_rcpf)
#define RCPF(x) __builtin_amdgcn_rcpf(x)
#else
#define RCPF(x) (1.0f / (x))
#endif

#define L2E 1.44269504088896340736f

__device__ __forceinline__ float fast_sig(float x) {
    return RCPF(1.0f + EXP2F(-x * L2E));
}
__device__ __forceinline__ float fast_tanh(float x) {
    float e = EXP2F(x * (2.0f * L2E));
    return 1.0f - 2.0f * RCPF(1.0f + e);
}
__device__ __forceinline__ void add4(float4& a, const float4 b) {
    a.x += b.x; a.y += b.y; a.z += b.z; a.w += b.w;
}

__global__ __launch_bounds__(256, 1) void cnn_lstm_kernel(
    const int* __restrict__ inp, const float* __restrict__ emb,
    const float* __restrict__ k2, const float* __restrict__ k3,
    const float* __restrict__ k4,
    const float* __restrict__ wfw, const float* __restrict__ bfw,
    const float* __restrict__ wbw, const float* __restrict__ bbw,
    float* __restrict__ out)
{
    // ctab[v][age][f]: contribution of char v seen `age` steps ago to the 12
    // conv outputs at the current position. Row SENT is all zeros.
    __shared__ float ctab[(VOCAB + 1) * TROW];
    // wlds[dir]: rows 0..21 = W (22 x 40 row-major), floats 880..919 = bias
    __shared__ float wlds[2 * WFLOATS];

    const int tid = threadIdx.x;

    // ---- stage weights into LDS --------------------------------------------
    for (int i = tid; i < WFLOATS; i += 256) {
        wlds[i]           = (i < 880) ? wfw[i] : bfw[i - 880];
        wlds[WFLOATS + i] = (i < 880) ? wbw[i] : bbw[i - 880];
    }

    // ---- build ctab: thread v = tid handles one vocab row ------------------
    {
        float er[EDIM];
        const float4* ep = (const float4*)(emb + tid * EDIM);
        float4 e0 = ep[0], e1 = ep[1], e2 = ep[2], e3 = ep[3];
        er[0] = e0.x; er[1] = e0.y; er[2] = e0.z; er[3] = e0.w;
        er[4] = e1.x; er[5] = e1.y; er[6] = e1.z; er[7] = e1.w;
        er[8] = e2.x; er[9] = e2.y; er[10] = e2.z; er[11] = e2.w;
        er[12] = e3.x; er[13] = e3.y; er[14] = e3.z; er[15] = e3.w;

        float* dst = ctab + tid * TROW;
        #pragma unroll
        for (int dlt = 0; dlt < 4; ++dlt) {
            float o[12];
            #pragma unroll
            for (int f = 0; f < 12; ++f) o[f] = 0.0f;
            const int tap2 = 1 - dlt, tap3 = 2 - dlt, tap4 = 3 - dlt;
            if (tap2 >= 0) {
                #pragma unroll
                for (int e = 0; e < EDIM; ++e) {
                    const float x = er[e];
                    #pragma unroll
                    for (int f = 0; f < 3; ++f) o[f] += x * k2[(tap2 * EDIM + e) * 3 + f];
                }
            }
            if (tap3 >= 0) {
                #pragma unroll
                for (int e = 0; e < EDIM; ++e) {
                    const float x = er[e];
                    #pragma unroll
                    for (int f = 0; f < 4; ++f) o[3 + f] += x * k3[(tap3 * EDIM + e) * 4 + f];
                }
            }
            {
                #pragma unroll
                for (int e = 0; e < EDIM; ++e) {
                    const float x = er[e];
                    #pragma unroll
                    for (int f = 0; f < 5; ++f) o[7 + f] += x * k4[(tap4 * EDIM + e) * 5 + f];
                }
            }
            #pragma unroll
            for (int f = 0; f < 12; ++f) dst[dlt * 12 + f] = o[f];
        }
    }
    if (tid < TROW) ctab[VOCAB * TROW + tid] = 0.0f;  // sentinel zero row
    __syncthreads();

    // ---- per-(sequence, direction) LSTM ------------------------------------
    const int dir = blockIdx.x >> 8;              // block-uniform
    const bool fw = (dir == 0);
    const int n = (blockIdx.x & 255) * 256 + tid;
    const int* inp_n = inp + n * SC;
    const float* ws = wlds + dir * WFLOATS;       // W rows (LDS)
    const float* bs = ws + 880;                   // bias (LDS)

    // xv = [conv feats (12), h (10)]  — the GEMV input vector, h kept in place
    float xv[22];
    float cs[HDIM];
    #pragma unroll
    for (int q = 0; q < HDIM; ++q) { xv[12 + q] = 0.0f; cs[q] = 0.0f; }

    // rolling chars at age 0..3 (a0 = current position's char)
    int a0, a1, a2, a3;
    if (fw) {
        a0 = inp_n[0]; a1 = SENT; a2 = SENT; a3 = SENT;
    } else {
        a0 = inp_n[SC - 1]; a1 = inp_n[SC - 2]; a2 = inp_n[SC - 3]; a3 = inp_n[SC - 4];
    }

    #pragma unroll 1
    for (int t = 0; t < SC; ++t) {
        // prefetch next char index at top; consumed at bottom of the body
        const int nidx = fw ? (t + 1) : (SC - 5 - t);
        int an = SENT;
        if ((t < SC - 1) && (nidx >= 0)) an = inp_n[nidx];

        // ---- conv outputs at this position: sum of 4 age-contributions ----
        const float4* r0 = (const float4*)(ctab + a0 * TROW);
        const float4* r1 = (const float4*)(ctab + a1 * TROW + 12);
        const float4* r2 = (const float4*)(ctab + a2 * TROW + 24);
        const float4* r3 = (const float4*)(ctab + a3 * TROW + 36);
        float4 C0 = r0[0], C1 = r0[1], C2 = r0[2];
        add4(C0, r1[0]); add4(C1, r1[1]); add4(C2, r1[2]);
        add4(C0, r2[0]); add4(C1, r2[1]); add4(C2, r2[2]);
        /* age-3 f0..3 block is all zeros -> skip */
        add4(C1, r3[1]); add4(C2, r3[2]);
        xv[0] = C0.x; xv[1] = C0.y; xv[2] = C0.z; xv[3] = C0.w;
        xv[4] = C1.x; xv[5] = C1.y; xv[6] = C1.z; xv[7] = C1.w;
        xv[8] = C2.x; xv[9] = C2.y; xv[10] = C2.z; xv[11] = C2.w;

        // ---- pass 1: gate columns 0..19 (i, j) -----------------------------
        float za[20];
        {
            const float4* bv = (const float4*)bs;
            #pragma unroll
            for (int j = 0; j < 5; ++j) {
                float4 b = bv[j];
                za[4 * j + 0] = b.x; za[4 * j + 1] = b.y;
                za[4 * j + 2] = b.z; za[4 * j + 3] = b.w;
            }
        }
        #pragma unroll
        for (int d = 0; d < 22; ++d) {
            const float xd = xv[d];
            const float4* wv = (const float4*)(ws + d * NG);
            #pragma unroll
            for (int j = 0; j < 5; ++j) {
                float4 w = wv[j];
                za[4 * j + 0] += xd * w.x;
                za[4 * j + 1] += xd * w.y;
                za[4 * j + 2] += xd * w.z;
                za[4 * j + 3] += xd * w.w;
            }
        }
        float ij[HDIM];
        #pragma unroll
        for (int q = 0; q < HDIM; ++q)
            ij[q] = fast_sig(za[q]) * fast_tanh(za[HDIM + q]);

        // ---- pass 2: gate columns 20..39 (f, o) ----------------------------
        float zb[20];
        {
            const float4* bv = (const float4*)(bs + 20);
            #pragma unroll
            for (int j = 0; j < 5; ++j) {
                float4 b = bv[j];
                zb[4 * j + 0] = b.x; zb[4 * j + 1] = b.y;
                zb[4 * j + 2] = b.z; zb[4 * j + 3] = b.w;
            }
        }
        #pragma unroll
        for (int d = 0; d < 22; ++d) {
            const float xd = xv[d];
            const float4* wv = (const float4*)(ws + d * NG + 20);
            #pragma unroll
            for (int j = 0; j < 5; ++j) {
                float4 w = wv[j];
                zb[4 * j + 0] += xd * w.x;
                zb[4 * j + 1] += xd * w.y;
                zb[4 * j + 2] += xd * w.z;
                zb[4 * j + 3] += xd * w.w;
            }
        }
        #pragma unroll
        for (int q = 0; q < HDIM; ++q) {
            const float fg = fast_sig(zb[q] + 1.0f);
            const float og = fast_sig(zb[HDIM + q]);
            cs[q] = fg * cs[q] + ij[q];
            xv[12 + q] = og * fast_tanh(cs[q]);
        }

        // ---- advance rolling char window -----------------------------------
        if (fw) { a3 = a2; a2 = a1; a1 = a0; a0 = an; }
        else    { a0 = a1; a1 = a2; a2 = a3; a3 = an; }
    }

    #pragma unroll
    for (int q = 0; q < HDIM; ++q)
        out[n * (2 * HDIM) + dir * HDIM + q] = xv[12 + q];
}

extern "C" void kernel_launch(void* const* d_in, const int* in_sizes, int n_in,
                              void* d_out, int out_size, void* d_ws, size_t ws_size,
                              hipStream_t stream) {
    const int*   inp = (const int*)d_in[0];
    const float* emb = (const float*)d_in[1];
    const float* k2  = (const float*)d_in[2];
    const float* k3  = (const float*)d_in[3];
    const float* k4  = (const float*)d_in[4];
    const float* wfw = (const float*)d_in[5];
    const float* bfw = (const float*)d_in[6];
    const float* wbw = (const float*)d_in[7];
    const float* bbw = (const float*)d_in[8];
    float* out = (float*)d_out;

    cnn_lstm_kernel<<<dim3(512), dim3(256), 0, stream>>>(
        inp, emb, k2, k3, k4, wfw, bfw, wbw, bbw, out);
}

// Round 5
// 144.029 us; speedup vs baseline: 62.5219x; 11.4728x over previous
//
#include <hip/hip_runtime.h>

#define SC 20
#define EDIM 16
#define HDIM 10
#define CO 12
#define NG 40          // 4*H
#define VOCAB 256
#define TROW 52        // padded ctab row stride (floats)
#define SENT VOCAB     // sentinel zero row index
#define WFLOATS 920    // 22*40 weights + 40 bias per direction

#if __has_builtin(__builtin_amdgcn_exp2f)
#define EXP2F(x) __builtin_amdgcn_exp2f(x)
#else
#define EXP2F(x) exp2f(x)
#endif
#if __has_builtin(__builtin_amdgcn_rcpf)
#define RCPF(x) __builtin_amdgcn_rcpf(x)
#else
#define RCPF(x) (1.0f / (x))
#endif

#define L2E 1.44269504088896340736f

__device__ __forceinline__ float fast_sig(float x) {
    return RCPF(1.0f + EXP2F(-x * L2E));
}
__device__ __forceinline__ float fast_tanh(float x) {
    float e = EXP2F(x * (2.0f * L2E));
    return 1.0f - 2.0f * RCPF(1.0f + e);
}
__device__ __forceinline__ void add4(float4& a, const float4 b) {
    a.x += b.x; a.y += b.y; a.z += b.z; a.w += b.w;
}

// one GEMV rank-1 update: acc[0..19] += x * w4[0..4]  (w4 = 5 float4 from LDS)
__device__ __forceinline__ void rank1(float* acc, float x, const float4* wv) {
    #pragma unroll
    for (int j = 0; j < 5; ++j) {
        float4 w = wv[j];
        acc[4 * j + 0] += x * w.x;
        acc[4 * j + 1] += x * w.y;
        acc[4 * j + 2] += x * w.z;
        acc[4 * j + 3] += x * w.w;
    }
}

__global__ __launch_bounds__(256, 1) void cnn_lstm_kernel(
    const int* __restrict__ inp, const float* __restrict__ emb,
    const float* __restrict__ k2, const float* __restrict__ k3,
    const float* __restrict__ k4,
    const float* __restrict__ wfw, const float* __restrict__ bfw,
    const float* __restrict__ wbw, const float* __restrict__ bbw,
    float* __restrict__ out)
{
    // ctab[v][age][f]: contribution of char v seen `age` steps ago to the 12
    // conv outputs at the current position. Row SENT is all zeros.
    __shared__ float ctab[(VOCAB + 1) * TROW];
    // wlds[dir]: rows 0..21 = W (22 x 40 row-major), floats 880..919 = bias
    __shared__ float wlds[2 * WFLOATS];

    const int tid = threadIdx.x;

    // ---- stage weights into LDS --------------------------------------------
    for (int i = tid; i < WFLOATS; i += 256) {
        wlds[i]           = (i < 880) ? wfw[i] : bfw[i - 880];
        wlds[WFLOATS + i] = (i < 880) ? wbw[i] : bbw[i - 880];
    }

    // ---- build ctab: thread v = tid handles one vocab row ------------------
    {
        float er[EDIM];
        const float4* ep = (const float4*)(emb + tid * EDIM);
        float4 e0 = ep[0], e1 = ep[1], e2 = ep[2], e3 = ep[3];
        er[0] = e0.x; er[1] = e0.y; er[2] = e0.z; er[3] = e0.w;
        er[4] = e1.x; er[5] = e1.y; er[6] = e1.z; er[7] = e1.w;
        er[8] = e2.x; er[9] = e2.y; er[10] = e2.z; er[11] = e2.w;
        er[12] = e3.x; er[13] = e3.y; er[14] = e3.z; er[15] = e3.w;

        float* dst = ctab + tid * TROW;
        #pragma unroll
        for (int dlt = 0; dlt < 4; ++dlt) {
            float o[12];
            #pragma unroll
            for (int f = 0; f < 12; ++f) o[f] = 0.0f;
            const int tap2 = 1 - dlt, tap3 = 2 - dlt, tap4 = 3 - dlt;
            if (tap2 >= 0) {
                #pragma unroll
                for (int e = 0; e < EDIM; ++e) {
                    const float x = er[e];
                    #pragma unroll
                    for (int f = 0; f < 3; ++f) o[f] += x * k2[(tap2 * EDIM + e) * 3 + f];
                }
            }
            if (tap3 >= 0) {
                #pragma unroll
                for (int e = 0; e < EDIM; ++e) {
                    const float x = er[e];
                    #pragma unroll
                    for (int f = 0; f < 4; ++f) o[3 + f] += x * k3[(tap3 * EDIM + e) * 4 + f];
                }
            }
            {
                #pragma unroll
                for (int e = 0; e < EDIM; ++e) {
                    const float x = er[e];
                    #pragma unroll
                    for (int f = 0; f < 5; ++f) o[7 + f] += x * k4[(tap4 * EDIM + e) * 5 + f];
                }
            }
            #pragma unroll
            for (int f = 0; f < 12; ++f) dst[dlt * 12 + f] = o[f];
        }
    }
    if (tid < TROW) ctab[VOCAB * TROW + tid] = 0.0f;  // sentinel zero row
    __syncthreads();

    // ---- per-(sequence, direction) LSTM ------------------------------------
    const int dir = blockIdx.x >> 8;              // block-uniform
    const bool fw = (dir == 0);
    const int n = (blockIdx.x & 255) * 256 + tid;
    const int* inp_n = inp + n * SC;
    const float* ws = wlds + dir * WFLOATS;       // W rows (LDS)
    const float* bs = ws + 880;                   // bias (LDS)

    // xv = [conv feats (12), h (10)]  — the GEMV input vector, h kept in place
    float xv[22];
    float cs[HDIM];
    #pragma unroll
    for (int q = 0; q < HDIM; ++q) { xv[12 + q] = 0.0f; cs[q] = 0.0f; }

    // rolling chars at age 0..3 (a0 = current position's char)
    int a0, a1, a2, a3;
    if (fw) {
        a0 = inp_n[0]; a1 = SENT; a2 = SENT; a3 = SENT;
    } else {
        a0 = inp_n[SC - 1]; a1 = inp_n[SC - 2]; a2 = inp_n[SC - 3]; a3 = inp_n[SC - 4];
    }

    #pragma unroll 1
    for (int t = 0; t < SC; ++t) {
        // prefetch next char index at top; consumed at bottom of the body
        const int nidx = fw ? (t + 1) : (SC - 5 - t);
        int an = SENT;
        if ((t < SC - 1) && (nidx >= 0)) an = inp_n[nidx];

        // ---- conv outputs at this position: sum of 4 age-contributions ----
        const float4* r0 = (const float4*)(ctab + a0 * TROW);
        const float4* r1 = (const float4*)(ctab + a1 * TROW + 12);
        const float4* r2 = (const float4*)(ctab + a2 * TROW + 24);
        const float4* r3 = (const float4*)(ctab + a3 * TROW + 36);
        float4 C0 = r0[0], C1 = r0[1], C2 = r0[2];
        add4(C0, r1[0]); add4(C1, r1[1]); add4(C2, r1[2]);
        add4(C0, r2[0]); add4(C1, r2[1]); add4(C2, r2[2]);
        /* age-3 f0..3 block is all zeros -> skip */
        add4(C1, r3[1]); add4(C2, r3[2]);
        xv[0] = C0.x; xv[1] = C0.y; xv[2] = C0.z; xv[3] = C0.w;
        xv[4] = C1.x; xv[5] = C1.y; xv[6] = C1.z; xv[7] = C1.w;
        xv[8] = C2.x; xv[9] = C2.y; xv[10] = C2.z; xv[11] = C2.w;
        __builtin_amdgcn_sched_barrier(0);   // don't batch GEMV loads into conv

        // ---- pass 1: gate columns 0..19 (i, j) -----------------------------
        float za[20];
        {
            const float4* bv = (const float4*)bs;
            #pragma unroll
            for (int j = 0; j < 5; ++j) {
                float4 b = bv[j];
                za[4 * j + 0] = b.x; za[4 * j + 1] = b.y;
                za[4 * j + 2] = b.z; za[4 * j + 3] = b.w;
            }
        }
        // d-loop chunked by 2: sched_barrier bounds in-flight ds_reads to <=10
        // (the full unroll otherwise batches ~110 b128 loads -> VGPR blowout)
        #pragma unroll
        for (int dd = 0; dd < 11; ++dd) {
            rank1(za, xv[2 * dd + 0], (const float4*)(ws + (2 * dd + 0) * NG));
            rank1(za, xv[2 * dd + 1], (const float4*)(ws + (2 * dd + 1) * NG));
            __builtin_amdgcn_sched_barrier(0);
        }
        float ij[HDIM];
        #pragma unroll
        for (int q = 0; q < HDIM; ++q)
            ij[q] = fast_sig(za[q]) * fast_tanh(za[HDIM + q]);

        // ---- pass 2: gate columns 20..39 (f, o) ----------------------------
        float zb[20];
        {
            const float4* bv = (const float4*)(bs + 20);
            #pragma unroll
            for (int j = 0; j < 5; ++j) {
                float4 b = bv[j];
                zb[4 * j + 0] = b.x; zb[4 * j + 1] = b.y;
                zb[4 * j + 2] = b.z; zb[4 * j + 3] = b.w;
            }
        }
        #pragma unroll
        for (int dd = 0; dd < 11; ++dd) {
            rank1(zb, xv[2 * dd + 0], (const float4*)(ws + (2 * dd + 0) * NG + 20));
            rank1(zb, xv[2 * dd + 1], (const float4*)(ws + (2 * dd + 1) * NG + 20));
            __builtin_amdgcn_sched_barrier(0);
        }
        #pragma unroll
        for (int q = 0; q < HDIM; ++q) {
            const float fg = fast_sig(zb[q] + 1.0f);
            const float og = fast_sig(zb[HDIM + q]);
            cs[q] = fg * cs[q] + ij[q];
            xv[12 + q] = og * fast_tanh(cs[q]);
        }

        // ---- advance rolling char window -----------------------------------
        if (fw) { a3 = a2; a2 = a1; a1 = a0; a0 = an; }
        else    { a0 = a1; a1 = a2; a2 = a3; a3 = an; }
    }

    #pragma unroll
    for (int q = 0; q < HDIM; ++q)
        out[n * (2 * HDIM) + dir * HDIM + q] = xv[12 + q];
}

extern "C" void kernel_launch(void* const* d_in, const int* in_sizes, int n_in,
                              void* d_out, int out_size, void* d_ws, size_t ws_size,
                              hipStream_t stream) {
    const int*   inp = (const int*)d_in[0];
    const float* emb = (const float*)d_in[1];
    const float* k2  = (const float*)d_in[2];
    const float* k3  = (const float*)d_in[3];
    const float* k4  = (const float*)d_in[4];
    const float* wfw = (const float*)d_in[5];
    const float* bfw = (const float*)d_in[6];
    const float* wbw = (const float*)d_in[7];
    const float* bbw = (const float*)d_in[8];
    float* out = (float*)d_out;

    cnn_lstm_kernel<<<dim3(512), dim3(256), 0, stream>>>(
        inp, emb, k2, k3, k4, wfw, bfw, wbw, bbw, out);
}